// Round 15
// baseline (149.305 us; speedup 1.0000x reference)
//
#include <hip/hip_runtime.h>
#include <hip/hip_bf16.h>
#include <stdint.h>

#define AS1 __attribute__((address_space(1)))
#define AS3 __attribute__((address_space(3)))

typedef __bf16 bf16x8 __attribute__((ext_vector_type(8)));
typedef float  f32x4  __attribute__((ext_vector_type(4)));
typedef float  f32x16 __attribute__((ext_vector_type(16)));
typedef unsigned short ushort8v __attribute__((ext_vector_type(8)));
typedef unsigned short ushort4v __attribute__((ext_vector_type(4)));
typedef short short8v __attribute__((ext_vector_type(8)));
typedef short short4v __attribute__((ext_vector_type(4)));

__device__ __forceinline__ unsigned short f2bf(float f) {
    unsigned int u = __float_as_uint(f);
    u += 0x7fffu + ((u >> 16) & 1u);           // round-to-nearest-even
    return (unsigned short)(u >> 16);
}
__device__ __forceinline__ unsigned int pk2bf(float a, float b) {
    __hip_bfloat162 h = __float22bfloat162_rn(make_float2(a, b));  // x->low short
    unsigned int u;
    __builtin_memcpy(&u, &h, 4);
    return u;
}
__device__ __forceinline__ void g2lds16(const void* gp, void* lp) {
    __builtin_amdgcn_global_load_lds((AS1 void*)gp, (AS3 void*)lp, 16, 0, 0);
}
#define E2(x) __builtin_amdgcn_exp2f(x)

// ---------------- cast fp32 -> bf16 (x, Wq, Wk, Wv in one launch) -----------
__global__ __launch_bounds__(256) void cast_all(const float* __restrict__ x,
                                                const float* __restrict__ w0,
                                                const float* __restrict__ w1,
                                                const float* __restrict__ w2,
                                                unsigned short* __restrict__ xb,
                                                unsigned short* __restrict__ wc) {
    int id = blockIdx.x;
    const float* s;
    unsigned short* d;
    int base;
    if (id < 4096) { s = x; d = xb; base = id; }
    else {
        int z = (id - 4096) >> 10;
        s = (z == 0) ? w0 : (z == 1) ? w1 : w2;
        d = wc + (size_t)z * 1048576;
        base = (id - 4096) & 1023;
    }
    int i = (base * 256 + threadIdx.x) * 4;
    float4 v = *(const float4*)(s + i);
    ushort4v o = { f2bf(v.x), f2bf(v.y), f2bf(v.z), f2bf(v.w) };
    *(ushort4v*)(d + i) = o;
}

// ---------------- QKV GEMM: R23 (measured == R21, kept) ---------------------
#define VMW(n) asm volatile("s_waitcnt vmcnt(" #n ")" ::: "memory")
#define NOW
#define PHCORE(STG, MFMAS, ENDW) do {                                          \
    STG;                                                                       \
    __builtin_amdgcn_s_barrier();                                              \
    asm volatile("s_waitcnt lgkmcnt(0)" ::: "memory");                         \
    __builtin_amdgcn_sched_barrier(0);                                         \
    __builtin_amdgcn_s_setprio(1);                                             \
    MFMAS;                                                                     \
    __builtin_amdgcn_s_setprio(0);                                             \
    __builtin_amdgcn_sched_barrier(0);                                         \
    ENDW;                                                                      \
    __builtin_amdgcn_s_barrier();                                              \
} while (0)

#define PHA(S, CUR, STG, ENDW) do {                                            \
    const int kx_ = ((S) * 32 + quad * 8) ^ ((cl & 7) * 8);                    \
    bf16x8 af_[4];                                                             \
    _Pragma("unroll")                                                          \
    for (int m_ = 0; m_ < 4; ++m_)                                             \
        af_[m_] = *(const bf16x8*)&SA[CUR][(rowA0 + m_ * 16) * 64 + kx_];      \
    _Pragma("unroll")                                                          \
    for (int n_ = 0; n_ < 3; ++n_)                                             \
        bqr[n_] = *(const bf16x8*)&SB[CUR][(rowB0 + n_ * 16) * 64 + kx_];      \
    PHCORE(STG,                                                                \
        _Pragma("unroll")                                                      \
        for (int m_ = 0; m_ < 4; ++m_)                                         \
            _Pragma("unroll")                                                  \
            for (int n_ = 0; n_ < 3; ++n_)                                     \
                acc[m_][n_] = __builtin_amdgcn_mfma_f32_16x16x32_bf16(         \
                    af_[m_], bqr[n_], acc[m_][n_], 0, 0, 0);                   \
        , ENDW);                                                               \
} while (0)

#define PHB(S, CUR, STG, ENDW) do {                                            \
    const int kx_ = ((S) * 32 + quad * 8) ^ ((cl & 7) * 8);                    \
    bf16x8 af_[4];                                                             \
    _Pragma("unroll")                                                          \
    for (int m_ = 0; m_ < 4; ++m_)                                             \
        af_[m_] = *(const bf16x8*)&SA[CUR][(rowA0 + 64 + m_ * 16) * 64 + kx_]; \
    PHCORE(STG,                                                                \
        _Pragma("unroll")                                                      \
        for (int m_ = 0; m_ < 4; ++m_)                                         \
            _Pragma("unroll")                                                  \
            for (int n_ = 0; n_ < 3; ++n_)                                     \
                acc[4 + m_][n_] = __builtin_amdgcn_mfma_f32_16x16x32_bf16(     \
                    af_[m_], bqr[n_], acc[4 + m_][n_], 0, 0, 0);               \
        , ENDW);                                                               \
} while (0)

__global__ __launch_bounds__(512, 2) void gemm_qkv(const unsigned short* __restrict__ X,
                                                   const unsigned short* __restrict__ W,
                                                   unsigned short* __restrict__ QKV) {
    const int K = 1024;
    const int b = blockIdx.x;                  // 256 blocks
    const int xcd = b & 7;                     // id%8 = XCD
    const int j = b >> 3;                      // 0..31
    const int m0 = (xcd * 2 + (j >> 4)) * 256; // 2 m-tiles per XCD
    const int n0 = (j & 15) * 192;             // 16 n-tiles over fused N=3072

    const float qs0 = 0.18033688011112042f;    // 0.125*log2(e) for Q (z==0)

    __shared__ unsigned short SA[2][16384];    // [buf][256 rows x 64 k]
    __shared__ unsigned short SB[2][12288];    // [buf][192 rows x 64 k]

    const int t = threadIdx.x;                 // 0..511
    const int w = t >> 6;
    const int l = t & 63;
    const int cl = l & 15;
    const int quad = l >> 4;
    const int rowA0 = (w >> 2) * 128 + cl;
    const int rowB0 = (w & 3) * 48 + cl;

    const int srow8 = t >> 3;                  // row within quarter 0..63
    const int klog = (((t & 7) ^ ((t >> 3) & 7)) * 8);
    const unsigned short* Abase = X + (size_t)(m0 + srow8) * K + klog;
    const unsigned short* Bbase = W + (size_t)(n0 + srow8) * K + klog;
    unsigned short* const sa0 = &SA[0][w * 512];
    unsigned short* const sa1 = &SA[1][w * 512];
    unsigned short* const sb0 = &SB[0][w * 512];
    unsigned short* const sb1 = &SB[1][w * 512];

    f32x4 acc[8][3] = {};
    bf16x8 bqr[3];

#define STGA(nb, q, k0) g2lds16(Abase + (size_t)(q) * 65536 + (k0), ((nb) ? sa1 : sa0) + (q) * 4096)
#define STGB(nb, q, k0) g2lds16(Bbase + (size_t)(q) * 65536 + (k0), ((nb) ? sb1 : sb0) + (q) * 4096)

    // prologue: tile 0 into buf 0 (A1,A3 newest)
    STGB(0, 0, 0); STGB(0, 1, 0); STGB(0, 2, 0);
    STGA(0, 0, 0); STGA(0, 2, 0); STGA(0, 1, 0); STGA(0, 3, 0);
    VMW(2);
    __builtin_amdgcn_s_barrier();

    for (int tt = 0; tt < 15; ++tt) {
        const int cur = tt & 1, nxt = cur ^ 1;
        const int k1 = (tt + 1) * 64;
        PHA(0, cur, { STGB(nxt, 0, k1); STGB(nxt, 1, k1); STGB(nxt, 2, k1); STGA(nxt, 0, k1); }, VMW(4));
        PHB(0, cur, { STGA(nxt, 2, k1); STGA(nxt, 1, k1); STGA(nxt, 3, k1); }, NOW);
        PHA(1, cur, {}, NOW);
        PHB(1, cur, {}, VMW(2));
    }
    // peeled tile 15 (cur = 1, no staging)
    PHA(0, 1, {}, VMW(0));
    PHB(0, 1, {}, NOW);
    PHA(1, 1, {}, NOW);
    PHB(1, 1, {}, NOW);

#undef STGA
#undef STGB

    #pragma unroll
    for (int mf = 0; mf < 8; ++mf) {
        #pragma unroll
        for (int rr = 0; rr < 4; ++rr) {
            size_t row = (size_t)(m0 + (w >> 2) * 128 + mf * 16 + quad * 4 + rr);
            #pragma unroll
            for (int nf = 0; nf < 3; ++nf) {
                const int nbase = n0 + (w & 3) * 48 + nf * 16;   // 16-aligned
                const int z = nbase >> 10;                        // run-uniform
                const float qs = (z == 0) ? qs0 : 1.0f;
                unsigned short* Cz = QKV + (size_t)z * 4194304;
                Cz[row * 1024 + ((nbase & 1023) + cl)] = f2bf(acc[mf][nf][rr] * qs);
            }
        }
    }
}

// ---------------- V swizzle to VT32 (per bh) --------------------------------
// R24: new V layout for the 32x32x16 PV. Per 64-kv chunk (4096 shorts):
//   off(τl, d) = (τl>>4)*1024 + (d>>5)*512 + ((τl>>3)&1)*256 + (d&31)*8 + (τl&7)
// so the PV A-fragment run (lane l: V[kvb*16 + h*8 + j][dblk*32 + (l&31)],
// j=0..7) is 16B-contiguous AND attn's LDS staging is fully linear (no
// swizzle needed; b128 reads stride 16B -> conflict-free by construction).
__global__ __launch_bounds__(256) void vtrans(const unsigned short* __restrict__ Vn,
                                              unsigned short* __restrict__ V32) {
    const int bh = blockIdx.y;
    const int T0 = blockIdx.x * 128;
    __shared__ unsigned short L[128 * 72];
    const int t = threadIdx.x;

    const unsigned short* src = Vn + (size_t)bh * 131072 + (size_t)T0 * 64;
    #pragma unroll
    for (int p = 0; p < 4; ++p) {
        int r = p * 32 + (t >> 3), c = (t & 7) * 8;
        *(ushort8v*)(L + r * 72 + c) = *(const ushort8v*)(src + (size_t)r * 64 + c);
    }
    __syncthreads();
    unsigned short* dst = V32 + (size_t)bh * 131072 + (size_t)(T0 >> 6) * 4096;
    #pragma unroll
    for (int cc = 0; cc < 2; ++cc) {
        #pragma unroll
        for (int p = 0; p < 2; ++p) {
            int i = p * 256 + t;               // granule 0..511 within chunk
            int kvb = i >> 7, dblk = (i >> 6) & 1, h = (i >> 5) & 1, dl = i & 31;
            ushort8v a;
            #pragma unroll
            for (int jj = 0; jj < 8; ++jj)
                a[jj] = L[(cc * 64 + kvb * 16 + h * 8 + jj) * 72 + dblk * 32 + dl];
            *(ushort8v*)(dst + cc * 4096 + i * 8) = a;
        }
    }
}

// ---------------- Flash attention: R24 32x32-shape, 32q/wave ----------------
// Pipe analysis (R21 @37us): LDS-read pipe dominant (768 cyc/chunk-CU) since
// every wave reads the full 16KB K+V chunk for 16 q. R19 halved reads via
// 2x q at 16x16 shape and lost to chain length at 2 waves/SIMD. R24 halves
// reads via the 32x32x16 SHAPE: 32 q/wave, 8 QK + 8 PV wide MFMAs per chunk
// (chain SHORTER than R21's 24), LDS floor 768->384 cyc. 128-thr blocks
// (2 waves x 32q = 64-row band), R21 balance strata, 2-buf sync, 32KB LDS,
// 4 blk/CU (4 independent barrier domains). K staging/swizzle unchanged
// (4 granules/thread); V staged LINEAR from VT32. P cross-half redistribution
// for the PV B-operand: 2 shfl_xor(...,32) + cndmask selects per kv16 block
// (derivation in session notes; verified symbol-by-symbol both halves).
// C/D map (m74/m101): col=lane&31, row=(reg&3)+8*(reg>>2)+4*(lane>>5).
__global__ __launch_bounds__(128, 2) void attn(const unsigned short* __restrict__ QK,
                                               const unsigned short* __restrict__ V32,
                                               float* __restrict__ Out) {
    const int id = blockIdx.x;                         // 1024 blocks
    const int g = id & 255;
    const int s4 = id >> 8;                            // stratum 0..3
    const int bh = g & 31;                             // 4 bh per XCD
    const int pp = g >> 5;                             // 0..7
    const int bb = (s4 == 0) ? (31 - pp)
                 : (s4 == 1) ? pp
                 : (s4 == 2) ? (23 - pp)
                             : (8 + pp);               // 64-row band
    const int t = threadIdx.x;                         // 0..127
    const int w = t >> 6;                              // wave 0..1
    const int l = t & 63;
    const int q32 = l & 31;
    const int h = l >> 5;

    const size_t bhoff = (size_t)bh * 131072;
    const unsigned short* Qb = QK + bhoff;
    const unsigned short* Kb = QK + (size_t)4194304 + bhoff;
    const unsigned short* Vb = V32 + bhoff;
    float* Ob = Out + bhoff;

    __shared__ unsigned short KVs[2][8192];            // per buf: K 4096 | V 4096

    // K staging: granule gidx = i*128+t, LDS dest gidx*8, R18-swizzled source
    int kOi[4];
    #pragma unroll
    for (int i = 0; i < 4; ++i) {
        int gi = i * 128 + t;
        kOi[i] = (gi >> 3) * 64 + (((gi & 7) ^ ((gi >> 3) & 7)) * 8);
    }
    const int vsrc0 = t * 8;                           // V: linear both sides
    const int lB = w * 512;                            // wave-uniform dest base

    const int nch = bb + 1;
    const int qbase = bb * 64 + w * 32;
    const int mrel = w * 32 + q32;                     // q row rel. band base

    // Q fragments (B-operand): lane: Q[qbase+q32][db*16 + h*8 + j]
    bf16x8 qf[4];
    {
        const unsigned short* qa = Qb + (size_t)(qbase + q32) * 64 + h * 8;
        #pragma unroll
        for (int db = 0; db < 4; ++db)
            qf[db] = *(const bf16x8*)(qa + db * 16);
    }

    f32x16 o0 = {}, o1 = {};
    float lps = 0.f;

#define STGC(cc, buf) do {                                                     \
    unsigned short* s_ = &KVs[buf][0];                                         \
    const size_t off_ = (size_t)(cc) * 4096;                                   \
    _Pragma("unroll")                                                          \
    for (int i_ = 0; i_ < 4; ++i_) {                                           \
        g2lds16(Kb + off_ + kOi[i_], s_ + i_ * 1024 + lB);                     \
        g2lds16(Vb + off_ + i_ * 1024 + vsrc0, s_ + 4096 + i_ * 1024 + lB);    \
    }                                                                          \
} while (0)

    STGC(0, 0);

    for (int c = 0; c < nch; ++c) {
        __syncthreads();                               // buf[c&1] ready
        if (c + 1 < nch) STGC(c + 1, (c + 1) & 1);
        const unsigned short* Kl = &KVs[c & 1][0];
        const unsigned short* Vl = Kl + 4096;
        const bool masked = (c == bb);

        // K fragments (A-operand): row = kvblk*32 + q32, k = db*16 + h*8 + j
        bf16x8 kf0[4], kf1[4];
        #pragma unroll
        for (int db = 0; db < 4; ++db) {
            const int kx = (db * 16 + h * 8) ^ ((l & 7) * 8);
            kf0[db] = *(const bf16x8*)(Kl + (q32) * 64 + kx);
            kf1[db] = *(const bf16x8*)(Kl + (32 + q32) * 64 + kx);
        }
        f32x16 st0 = {}, st1 = {};
        __builtin_amdgcn_s_setprio(1);
        #pragma unroll
        for (int db = 0; db < 4; ++db) {
            st0 = __builtin_amdgcn_mfma_f32_32x32x16_bf16(kf0[db], qf[db], st0, 0, 0, 0);
            st1 = __builtin_amdgcn_mfma_f32_32x32x16_bf16(kf1[db], qf[db], st1, 0, 0, 0);
        }
        __builtin_amdgcn_s_setprio(0);

        // p = exp2(masked scores); pack; lps
        unsigned int u[2][8];
        #pragma unroll
        for (int kvblk = 0; kvblk < 2; ++kvblk) {
            const f32x16 stx = kvblk ? st1 : st0;
            #pragma unroll
            for (int s = 0; s < 8; ++s) {
                float pa, pbv;
                {
                    const int r = 2 * s;
                    const int kvloc = kvblk * 32 + 4 * h + (r & 3) + 8 * (r >> 2);
                    pa = (!masked || kvloc <= mrel) ? E2(stx[r]) : 0.f;
                }
                {
                    const int r = 2 * s + 1;
                    const int kvloc = kvblk * 32 + 4 * h + (r & 3) + 8 * (r >> 2);
                    pbv = (!masked || kvloc <= mrel) ? E2(stx[r]) : 0.f;
                }
                lps += pa + pbv;
                u[kvblk][s] = pk2bf(pa, pbv);
            }
        }

        // PV B-operands: cross-half redistribution (2 shfl_xor + selects /kvb)
        bf16x8 pb[4];
        #pragma unroll
        for (int kvb = 0; kvb < 4; ++kvb) {
            const int kb = kvb >> 1, b1 = kvb & 1;
            const unsigned int A0 = u[kb][4 * b1 + 0], A1 = u[kb][4 * b1 + 1];
            const unsigned int B0 = u[kb][4 * b1 + 2], B1 = u[kb][4 * b1 + 3];
            const unsigned int s0 = h ? A0 : B0;
            const unsigned int s1 = h ? A1 : B1;
            const unsigned int r0 = (unsigned int)__shfl_xor((int)s0, 32);
            const unsigned int r1 = (unsigned int)__shfl_xor((int)s1, 32);
            unsigned int vals[4];
            vals[0] = h ? r0 : A0;                     // j0,j1 (half0's)
            vals[1] = h ? r1 : A1;                     // j2,j3
            vals[2] = h ? B0 : r0;                     // j4,j5 (half1's)
            vals[3] = h ? B1 : r1;                     // j6,j7
            __builtin_memcpy(&pb[kvb], vals, 16);
        }

        // PV: A = V^T frags (linear VT32 LDS), 8 MFMA
        __builtin_amdgcn_s_setprio(1);
        #pragma unroll
        for (int kvb = 0; kvb < 4; ++kvb) {
            const bf16x8 vfa = *(const bf16x8*)(Vl + kvb * 1024 + h * 256 + q32 * 8);
            const bf16x8 vfb = *(const bf16x8*)(Vl + kvb * 1024 + 512 + h * 256 + q32 * 8);
            o0 = __builtin_amdgcn_mfma_f32_32x32x16_bf16(vfa, pb[kvb], o0, 0, 0, 0);
            o1 = __builtin_amdgcn_mfma_f32_32x32x16_bf16(vfb, pb[kvb], o1, 0, 0, 0);
        }
        __builtin_amdgcn_s_setprio(0);
    }
#undef STGC

    lps += __shfl_xor(lps, 32);
    const float inv = 1.0f / lps;
    float* const ob = Ob + (size_t)(qbase + q32) * 64 + 4 * h;
    #pragma unroll
    for (int rq = 0; rq < 4; ++rq) {
        f32x4 ra = { o0[rq * 4 + 0] * inv, o0[rq * 4 + 1] * inv,
                     o0[rq * 4 + 2] * inv, o0[rq * 4 + 3] * inv };
        *(f32x4*)(ob + 8 * rq) = ra;
        f32x4 rb = { o1[rq * 4 + 0] * inv, o1[rq * 4 + 1] * inv,
                     o1[rq * 4 + 2] * inv, o1[rq * 4 + 3] * inv };
        *(f32x4*)(ob + 32 + 8 * rq) = rb;
    }
}

extern "C" void kernel_launch(void* const* d_in, const int* in_sizes, int n_in,
                              void* d_out, int out_size, void* d_ws, size_t ws_size,
                              hipStream_t stream) {
    const float* x  = (const float*)d_in[0];
    const float* Wq = (const float*)d_in[1];
    const float* Wk = (const float*)d_in[2];
    const float* Wv = (const float*)d_in[3];
    float* out = (float*)d_out;

    // ws: xb 8MB | wc 6MB | QKV natural 24MB | VT32 8MB = 46MB
    unsigned short* xb  = (unsigned short*)d_ws;
    unsigned short* wc  = xb + (size_t)4096 * 1024;
    unsigned short* qkv = wc + (size_t)3 * 1024 * 1024;
    unsigned short* vt  = qkv + (size_t)3 * 4096 * 1024;

    hipLaunchKernelGGL(cast_all, dim3(7168), dim3(256), 0, stream, x, Wq, Wk, Wv, xb, wc);
    hipLaunchKernelGGL(gemm_qkv, dim3(256), dim3(512), 0, stream, xb, wc, qkv);
    hipLaunchKernelGGL(vtrans, dim3(16, 32), dim3(256), 0, stream, qkv + (size_t)2 * 4096 * 1024, vt);
    hipLaunchKernelGGL(attn, dim3(1024), dim3(128), 0, stream, qkv, vt, out);
}

// Round 16
// 138.714 us; speedup vs baseline: 1.0764x; 1.0764x over previous
//
#include <hip/hip_runtime.h>
#include <hip/hip_bf16.h>
#include <stdint.h>

#define AS1 __attribute__((address_space(1)))
#define AS3 __attribute__((address_space(3)))

typedef __bf16 bf16x8 __attribute__((ext_vector_type(8)));
typedef float  f32x4  __attribute__((ext_vector_type(4)));
typedef unsigned short ushort8v __attribute__((ext_vector_type(8)));
typedef unsigned short ushort4v __attribute__((ext_vector_type(4)));
typedef short short8v __attribute__((ext_vector_type(8)));
typedef short short4v __attribute__((ext_vector_type(4)));

__device__ __forceinline__ unsigned short f2bf(float f) {
    unsigned int u = __float_as_uint(f);
    u += 0x7fffu + ((u >> 16) & 1u);           // round-to-nearest-even
    return (unsigned short)(u >> 16);
}
__device__ __forceinline__ unsigned int pk2bf(float a, float b) {
    __hip_bfloat162 h = __float22bfloat162_rn(make_float2(a, b));  // x->low short
    unsigned int u;
    __builtin_memcpy(&u, &h, 4);
    return u;
}
__device__ __forceinline__ void g2lds16(const void* gp, void* lp) {
    __builtin_amdgcn_global_load_lds((AS1 void*)gp, (AS3 void*)lp, 16, 0, 0);
}
#define E2(x) __builtin_amdgcn_exp2f(x)

// ---------------- cast fp32 -> bf16 (x, Wq, Wk, Wv in one launch) -----------
__global__ __launch_bounds__(256) void cast_all(const float* __restrict__ x,
                                                const float* __restrict__ w0,
                                                const float* __restrict__ w1,
                                                const float* __restrict__ w2,
                                                unsigned short* __restrict__ xb,
                                                unsigned short* __restrict__ wc) {
    int id = blockIdx.x;
    const float* s;
    unsigned short* d;
    int base;
    if (id < 4096) { s = x; d = xb; base = id; }
    else {
        int z = (id - 4096) >> 10;
        s = (z == 0) ? w0 : (z == 1) ? w1 : w2;
        d = wc + (size_t)z * 1048576;
        base = (id - 4096) & 1023;
    }
    int i = (base * 256 + threadIdx.x) * 4;
    float4 v = *(const float4*)(s + i);
    ushort4v o = { f2bf(v.x), f2bf(v.y), f2bf(v.z), f2bf(v.w) };
    *(ushort4v*)(d + i) = o;
}

// ---------------- QKV GEMM: R21 (measured best — fused N3072, XCD-pinned) ---
// Converged: R23's deeper staging cover measured == R21; 8-phase 256x192
// structure at its local optimum (~33us, 100% CU coverage).
#define VMW(n) asm volatile("s_waitcnt vmcnt(" #n ")" ::: "memory")
#define NOW
#define PHCORE(STG, MFMAS, ENDW) do {                                          \
    STG;                                                                       \
    __builtin_amdgcn_s_barrier();                                              \
    asm volatile("s_waitcnt lgkmcnt(0)" ::: "memory");                         \
    __builtin_amdgcn_sched_barrier(0);                                         \
    __builtin_amdgcn_s_setprio(1);                                             \
    MFMAS;                                                                     \
    __builtin_amdgcn_s_setprio(0);                                             \
    __builtin_amdgcn_sched_barrier(0);                                         \
    ENDW;                                                                      \
    __builtin_amdgcn_s_barrier();                                              \
} while (0)

// PHA: reads 4 A frags (low half) + 3 B frags (kept in bqr for PHB)
#define PHA(S, CUR, STG, ENDW) do {                                            \
    const int kx_ = ((S) * 32 + quad * 8) ^ ((cl & 7) * 8);                    \
    bf16x8 af_[4];                                                             \
    _Pragma("unroll")                                                          \
    for (int m_ = 0; m_ < 4; ++m_)                                             \
        af_[m_] = *(const bf16x8*)&SA[CUR][(rowA0 + m_ * 16) * 64 + kx_];      \
    _Pragma("unroll")                                                          \
    for (int n_ = 0; n_ < 3; ++n_)                                             \
        bqr[n_] = *(const bf16x8*)&SB[CUR][(rowB0 + n_ * 16) * 64 + kx_];      \
    PHCORE(STG,                                                                \
        _Pragma("unroll")                                                      \
        for (int m_ = 0; m_ < 4; ++m_)                                         \
            _Pragma("unroll")                                                  \
            for (int n_ = 0; n_ < 3; ++n_)                                     \
                acc[m_][n_] = __builtin_amdgcn_mfma_f32_16x16x32_bf16(         \
                    af_[m_], bqr[n_], acc[m_][n_], 0, 0, 0);                   \
        , ENDW);                                                               \
} while (0)

// PHB: reads 4 A frags (high half) only, reuses bqr
#define PHB(S, CUR, STG, ENDW) do {                                            \
    const int kx_ = ((S) * 32 + quad * 8) ^ ((cl & 7) * 8);                    \
    bf16x8 af_[4];                                                             \
    _Pragma("unroll")                                                          \
    for (int m_ = 0; m_ < 4; ++m_)                                             \
        af_[m_] = *(const bf16x8*)&SA[CUR][(rowA0 + 64 + m_ * 16) * 64 + kx_]; \
    PHCORE(STG,                                                                \
        _Pragma("unroll")                                                      \
        for (int m_ = 0; m_ < 4; ++m_)                                         \
            _Pragma("unroll")                                                  \
            for (int n_ = 0; n_ < 3; ++n_)                                     \
                acc[4 + m_][n_] = __builtin_amdgcn_mfma_f32_16x16x32_bf16(     \
                    af_[m_], bqr[n_], acc[4 + m_][n_], 0, 0, 0);               \
        , ENDW);                                                               \
} while (0)

__global__ __launch_bounds__(512, 2) void gemm_qkv(const unsigned short* __restrict__ X,
                                                   const unsigned short* __restrict__ W,
                                                   unsigned short* __restrict__ QKV) {
    const int K = 1024;
    const int b = blockIdx.x;                  // 256 blocks
    const int xcd = b & 7;                     // id%8 = XCD
    const int j = b >> 3;                      // 0..31
    const int m0 = (xcd * 2 + (j >> 4)) * 256; // 2 m-tiles per XCD
    const int n0 = (j & 15) * 192;             // 16 n-tiles over fused N=3072

    const float qs0 = 0.18033688011112042f;    // 0.125*log2(e) for Q (z==0)

    __shared__ unsigned short SA[2][16384];    // [buf][256 rows x 64 k]
    __shared__ unsigned short SB[2][12288];    // [buf][192 rows x 64 k]

    const int t = threadIdx.x;                 // 0..511
    const int w = t >> 6;
    const int l = t & 63;
    const int cl = l & 15;
    const int quad = l >> 4;
    const int rowA0 = (w >> 2) * 128 + cl;
    const int rowB0 = (w & 3) * 48 + cl;

    const int srow8 = t >> 3;                  // row within quarter 0..63
    const int klog = (((t & 7) ^ ((t >> 3) & 7)) * 8);
    const unsigned short* Abase = X + (size_t)(m0 + srow8) * K + klog;
    const unsigned short* Bbase = W + (size_t)(n0 + srow8) * K + klog;
    unsigned short* const sa0 = &SA[0][w * 512];
    unsigned short* const sa1 = &SA[1][w * 512];
    unsigned short* const sb0 = &SB[0][w * 512];
    unsigned short* const sb1 = &SB[1][w * 512];

    f32x4 acc[8][3] = {};
    bf16x8 bqr[3];

#define STGA(nb, q, k0) g2lds16(Abase + (size_t)(q) * 65536 + (k0), ((nb) ? sa1 : sa0) + (q) * 4096)
#define STGB(nb, q, k0) g2lds16(Bbase + (size_t)(q) * 65536 + (k0), ((nb) ? sb1 : sb0) + (q) * 4096)

    // prologue: tile 0 into buf 0 (issue order = steady-state; A1,A3 newest)
    STGB(0, 0, 0); STGB(0, 1, 0); STGB(0, 2, 0);
    STGA(0, 0, 0); STGA(0, 2, 0); STGA(0, 1, 0); STGA(0, 3, 0);
    VMW(2);
    __builtin_amdgcn_s_barrier();

    for (int tt = 0; tt < 15; ++tt) {
        const int cur = tt & 1, nxt = cur ^ 1;
        const int k1 = (tt + 1) * 64;
        PHA(0, cur, { STGB(nxt, 0, k1); STGB(nxt, 1, k1); }, VMW(2));
        PHB(0, cur, { STGB(nxt, 2, k1); STGA(nxt, 0, k1); }, NOW);
        PHA(1, cur, { STGA(nxt, 2, k1); STGA(nxt, 1, k1); }, NOW);
        PHB(1, cur, { STGA(nxt, 3, k1); },                   VMW(2));
    }
    // peeled tile 15 (cur = 1, no staging)
    PHA(0, 1, {}, VMW(0));
    PHB(0, 1, {}, NOW);
    PHA(1, 1, {}, NOW);
    PHB(1, 1, {}, NOW);

#undef STGA
#undef STGB

    #pragma unroll
    for (int mf = 0; mf < 8; ++mf) {
        #pragma unroll
        for (int rr = 0; rr < 4; ++rr) {
            size_t row = (size_t)(m0 + (w >> 2) * 128 + mf * 16 + quad * 4 + rr);
            #pragma unroll
            for (int nf = 0; nf < 3; ++nf) {
                const int nbase = n0 + (w & 3) * 48 + nf * 16;   // 16-aligned
                const int z = nbase >> 10;                        // run-uniform
                const float qs = (z == 0) ? qs0 : 1.0f;
                unsigned short* Cz = QKV + (size_t)z * 4194304;
                Cz[row * 1024 + ((nbase & 1023) + cl)] = f2bf(acc[mf][nf][rr] * qs);
            }
        }
    }
}

// ---------------- V swizzle to VT3 (per bh) ---------------------------------
// VT3 element (tau, d) at (tau>>4)*1024 + (d&15)*64 + ((tau>>2)&3)*16
//                        + (d>>4)*4 + (tau&3)
__global__ __launch_bounds__(256) void vtrans(const unsigned short* __restrict__ Vn,
                                              unsigned short* __restrict__ V3) {
    const int bh = blockIdx.y;
    const int T0 = blockIdx.x * 128;
    __shared__ unsigned short L[128 * 72];
    const int t = threadIdx.x;

    const unsigned short* src = Vn + (size_t)bh * 131072 + (size_t)T0 * 64;
    #pragma unroll
    for (int p = 0; p < 4; ++p) {
        int r = p * 32 + (t >> 3), c = (t & 7) * 8;
        *(ushort8v*)(L + r * 72 + c) = *(const ushort8v*)(src + (size_t)r * 64 + c);
    }
    __syncthreads();
    unsigned short* dst = V3 + (size_t)bh * 131072 + (size_t)(T0 >> 4) * 1024;
    #pragma unroll
    for (int p = 0; p < 2; ++p) {
        int item = p * 256 + t;                 // 512 items: kb(8) x cl(16) x qk(4)
        int kb = item >> 6, cl = (item >> 2) & 15, qk = item & 3;
        ushort8v a, b;
        #pragma unroll
        for (int u = 0; u < 8; ++u) {
            int dt = u >> 2, j = u & 3;
            a[u] = L[(kb * 16 + qk * 4 + j) * 72 + dt * 16 + cl];
            b[u] = L[(kb * 16 + qk * 4 + j) * 72 + (dt + 2) * 16 + cl];
        }
        unsigned short* dp = dst + kb * 1024 + cl * 64 + qk * 16;
        *(ushort8v*)(dp) = a;
        *(ushort8v*)(dp + 8) = b;
    }
}

// ---------------- Flash attention: R21 (measured best) ----------------------
// Converged after 5 structural attempts: occupancy >=4 waves/SIMD is the
// binding constraint (R19/R24 at 2/SIMD: 48-50us despite halved LDS reads;
// R22 3-buf at 3/SIMD: neutral). R21 = 4-wave blocks, 4 blk/CU, exact per-CU
// balance (every CU sums to 66 chunks via 4 dispatch strata), heavy-first.
__global__ __launch_bounds__(256, 4) void attn(const unsigned short* __restrict__ QK,
                                               const unsigned short* __restrict__ V3,
                                               float* __restrict__ Out) {
    const int id = blockIdx.x;                         // 1024 blocks
    const int g = id & 255;
    const int s4 = id >> 8;                            // stratum 0..3
    const int bh = g & 31;                             // 4 bh per XCD (id%8 = XCD)
    const int pp = g >> 5;                             // 0..7
    const int bb = (s4 == 0) ? (31 - pp)
                 : (s4 == 1) ? pp
                 : (s4 == 2) ? (23 - pp)
                             : (8 + pp);               // 64-row band
    const int t = threadIdx.x;                         // 0..255
    const int w = t >> 6;                              // wave 0..3
    const int l = t & 63;
    const int cl = l & 15;
    const int quad = l >> 4;
    const int c7 = cl & 7;

    const size_t bhoff = (size_t)bh * 131072;
    const unsigned short* Qb = QK + bhoff;
    const unsigned short* Kb = QK + (size_t)4194304 + bhoff;
    const unsigned short* Vb = V3 + bhoff;
    float* Ob = Out + bhoff;

    __shared__ unsigned short KVs[2][8192];            // per buf: K 4096 | V 4096

    // staging: thread t stages granules t and t+256 of K and of V (R9 maps)
    const int g2 = t + 256;
    const int kO1 = (t >> 3) * 64 + (((t & 7) ^ ((t >> 3) & 7)) * 8);
    const int kO2 = (g2 >> 3) * 64 + (((g2 & 7) ^ ((g2 >> 3) & 7)) * 8);
    const int wg1 = t & 63;
    const int wg2 = g2 & 63;
    const int vO1 = (t >> 6) * 512 + ((wg1 ^ ((wg1 >> 3) & 7)) * 8);
    const int vO2 = (g2 >> 6) * 512 + ((wg2 ^ ((wg2 >> 3) & 7)) * 8);
    const int lB1 = w * 512;                           // shorts (wave-uniform)
    const int lB2 = 2048 + w * 512;

    // read offsets (R9-verified)
    const int oK0 = cl * 64 + (((quad)     ^ c7) * 8);
    const int oK1 = cl * 64 + (((quad + 4) ^ c7) * 8);
    const int oV0 = cl * 64 + (((quad * 2)     ^ c7) * 8);
    const int oV1 = cl * 64 + (((quad * 2 + 1) ^ c7) * 8);

    const int mrel = w * 16 + cl;                      // diag row rel. chunk base
    const int nch = bb + 1;                            // chunks for this band
    const int m0w = bb * 64 + w * 16;

    bf16x8 qf0, qf1;
    {
        const unsigned short* qa = Qb + (size_t)(m0w + cl) * 64 + quad * 8;
        qf0 = *(const bf16x8*)(qa);
        qf1 = *(const bf16x8*)(qa + 32);
    }

    f32x4 o[4] = {};
    float lps = 0.f;

    // stage chunk 0 into buf 0
    {
        unsigned short* s = &KVs[0][0];
        g2lds16(Kb + kO1, s + lB1);
        g2lds16(Kb + kO2, s + lB2);
        g2lds16(Vb + vO1, s + 4096 + lB1);
        g2lds16(Vb + vO2, s + 4096 + lB2);
    }

    for (int c = 0; c < nch; ++c) {
        __syncthreads();                               // buf[c&1] ready
        if (c + 1 < nch) {
            unsigned short* s = &KVs[(c + 1) & 1][0];
            const size_t off = (size_t)(c + 1) * 4096;
            g2lds16(Kb + off + kO1, s + lB1);
            g2lds16(Kb + off + kO2, s + lB2);
            g2lds16(Vb + off + vO1, s + 4096 + lB1);
            g2lds16(Vb + off + vO2, s + 4096 + lB2);
        }
        const unsigned short* Kl = &KVs[c & 1][0];
        const unsigned short* Vl = Kl + 4096;
        const bool masked = (c == bb);

        bf16x8 kf0[4], kf1[4];
        #pragma unroll
        for (int kt = 0; kt < 4; ++kt) {
            kf0[kt] = *(const bf16x8*)(Kl + kt * 1024 + oK0);
            kf1[kt] = *(const bf16x8*)(Kl + kt * 1024 + oK1);
        }
        f32x4 st[4] = {};
        __builtin_amdgcn_s_setprio(1);
        #pragma unroll
        for (int kt = 0; kt < 4; ++kt) {
            st[kt] = __builtin_amdgcn_mfma_f32_16x16x32_bf16(kf0[kt], qf0, st[kt], 0, 0, 0);
            st[kt] = __builtin_amdgcn_mfma_f32_16x16x32_bf16(kf1[kt], qf1, st[kt], 0, 0, 0);
        }
        __builtin_amdgcn_s_setprio(0);

        short4v pb[4];
        #pragma unroll
        for (int kt = 0; kt < 4; ++kt) {
            float p0, p1, p2, p3;
            if (masked) {
                const int lk = kt * 16 + quad * 4;
                p0 = (lk     <= mrel) ? E2(st[kt][0]) : 0.f;
                p1 = (lk + 1 <= mrel) ? E2(st[kt][1]) : 0.f;
                p2 = (lk + 2 <= mrel) ? E2(st[kt][2]) : 0.f;
                p3 = (lk + 3 <= mrel) ? E2(st[kt][3]) : 0.f;
            } else {
                p0 = E2(st[kt][0]);
                p1 = E2(st[kt][1]);
                p2 = E2(st[kt][2]);
                p3 = E2(st[kt][3]);
            }
            lps += (p0 + p1) + (p2 + p3);
            uint2 u = { pk2bf(p0, p1), pk2bf(p2, p3) };
            short4v pv;
            __builtin_memcpy(&pv, &u, 8);
            pb[kt] = pv;
        }

        __builtin_amdgcn_s_setprio(1);
        #pragma unroll
        for (int kt = 0; kt < 4; ++kt) {
            short8v v0 = *(const short8v*)(Vl + kt * 1024 + oV0);  // dt 0,1
            short8v v1 = *(const short8v*)(Vl + kt * 1024 + oV1);  // dt 2,3
            short4v a0 = __builtin_shufflevector(v0, v0, 0, 1, 2, 3);
            short4v a1 = __builtin_shufflevector(v0, v0, 4, 5, 6, 7);
            short4v a2 = __builtin_shufflevector(v1, v1, 0, 1, 2, 3);
            short4v a3 = __builtin_shufflevector(v1, v1, 4, 5, 6, 7);
            o[0] = __builtin_amdgcn_mfma_f32_16x16x16bf16_1k(a0, pb[kt], o[0], 0, 0, 0);
            o[1] = __builtin_amdgcn_mfma_f32_16x16x16bf16_1k(a1, pb[kt], o[1], 0, 0, 0);
            o[2] = __builtin_amdgcn_mfma_f32_16x16x16bf16_1k(a2, pb[kt], o[2], 0, 0, 0);
            o[3] = __builtin_amdgcn_mfma_f32_16x16x16bf16_1k(a3, pb[kt], o[3], 0, 0, 0);
        }
        __builtin_amdgcn_s_setprio(0);
    }

    lps += __shfl_xor(lps, 16);
    lps += __shfl_xor(lps, 32);
    const float inv = 1.0f / lps;
    #pragma unroll
    for (int dt = 0; dt < 4; ++dt) {
        f32x4 r = o[dt];
        r[0] *= inv; r[1] *= inv; r[2] *= inv; r[3] *= inv;
        *(f32x4*)(Ob + (size_t)(m0w + cl) * 64 + dt * 16 + quad * 4) = r;
    }
}

extern "C" void kernel_launch(void* const* d_in, const int* in_sizes, int n_in,
                              void* d_out, int out_size, void* d_ws, size_t ws_size,
                              hipStream_t stream) {
    const float* x  = (const float*)d_in[0];
    const float* Wq = (const float*)d_in[1];
    const float* Wk = (const float*)d_in[2];
    const float* Wv = (const float*)d_in[3];
    float* out = (float*)d_out;

    // ws: xb 8MB | wc 6MB | QKV natural 24MB | VT3 8MB = 46MB
    unsigned short* xb  = (unsigned short*)d_ws;
    unsigned short* wc  = xb + (size_t)4096 * 1024;
    unsigned short* qkv = wc + (size_t)3 * 1024 * 1024;
    unsigned short* vt  = qkv + (size_t)3 * 4096 * 1024;

    hipLaunchKernelGGL(cast_all, dim3(7168), dim3(256), 0, stream, x, Wq, Wk, Wv, xb, wc);
    hipLaunchKernelGGL(gemm_qkv, dim3(256), dim3(512), 0, stream, xb, wc, qkv);
    hipLaunchKernelGGL(vtrans, dim3(16, 32), dim3(256), 0, stream, qkv + (size_t)2 * 4096 * 1024, vt);
    hipLaunchKernelGGL(attn, dim3(1024), dim3(256), 0, stream, qkv, vt, out);
}